// Round 2
// baseline (893.528 us; speedup 1.0000x reference)
//
#include <hip/hip_runtime.h>
#include <math.h>

// Problem constants
#define HID   768
#define DIMD  192
#define NSIG  15
#define BB    32
#define SS    4096
#define SC    256                 // tokens per fused block
#define NCHUNK (SS / SC)          // 16
#define HC    32                  // h-cols staged per iteration
#define INV_SCALE 0.07216878364870322f   // 1/sqrt(192)
#define LOG_S     8.31776616671934f      // ln(4096)

// Workspace layout (floats)
#define WS_QK   ((size_t)0)                      // [15][768] scaled Q
#define WS_QB   (WS_QK + NSIG * HID)             // [15] scaled bias dot
#define WS_ST   (WS_QB + 16)                     // [B][16][15][3] m,l,pa partials
#define WS_CTXP (WS_ST + (size_t)BB * NCHUNK * NSIG * 3)  // [B][16][15][768]

// ---------------- Kernel A: Qk[n][h] = (q[n,:]·Wk[h,:])/sqrt(d), qb[n] = (q[n]·bk)/sqrt(d)
__global__ __launch_bounds__(256) void k_qk(const float* __restrict__ q,
                                            const float* __restrict__ Wk,
                                            const float* __restrict__ bk,
                                            float* __restrict__ ws) {
  int idx = blockIdx.x * 256 + threadIdx.x;
  if (idx < NSIG * HID) {
    int n = idx / HID, h = idx - n * HID;
    const float* qr = q + n * DIMD;
    const float* wr = Wk + h * DIMD;
    float s = 0.f;
    #pragma unroll 4
    for (int d = 0; d < DIMD; ++d) s = fmaf(qr[d], wr[d], s);
    ws[WS_QK + (size_t)n * HID + h] = s * INV_SCALE;
  }
  if (idx < NSIG) {
    const float* qr = q + idx * DIMD;
    float s = 0.f;
    for (int d = 0; d < DIMD; ++d) s = fmaf(qr[d], bk[d], s);
    ws[WS_QB + idx] = s * INV_SCALE;
  }
}

// ---------------- Fused kernel: logits -> local softmax partials -> ctx partials
// Block = (chunk of 256 tokens, b). LDS = X staging only (33.8 KB -> 4 blocks/CU).
// Q read via wave-uniform scalar loads (SMEM pipe). X re-read in pass B hits L3.
__global__ __launch_bounds__(256) void k_fused(const float* __restrict__ X,
                                               const float* __restrict__ qk,
                                               const float* __restrict__ qb,
                                               float* __restrict__ stats,
                                               float* __restrict__ ctxp) {
  __shared__ float smem[SC * (HC + 1)];   // 33792 B; reused as wS+red after pass A
  const int t = threadIdx.x;
  const int chunk = blockIdx.x, b = blockIdx.y;
  const int s0 = chunk * SC;
  const float* Xb = X + ((size_t)(b * SS + s0)) * HID;

  // ---- Pass A: logits for this block's 256 tokens (thread = token)
  float acc[NSIG];
  #pragma unroll
  for (int n = 0; n < NSIG; ++n) acc[n] = qb[n];

  for (int c = 0; c < HID / HC; ++c) {     // 24 h-chunks
    __syncthreads();
    // stage X[256][32] -> LDS (pad row to 33), coalesced float4 loads
    #pragma unroll
    for (int k = 0; k < 8; ++k) {
      int j = t + k * 256;                 // float4 index [0,2048)
      int r = j >> 3, cc = j & 7;
      float4 xv = *(const float4*)(Xb + (size_t)r * HID + c * HC + cc * 4);
      float* dst = smem + r * (HC + 1) + cc * 4;
      dst[0] = xv.x; dst[1] = xv.y; dst[2] = xv.z; dst[3] = xv.w;
    }
    __syncthreads();
    // x into registers once, reused across all 15 signals
    const float* xrow = smem + t * (HC + 1);
    float x[HC];
    #pragma unroll
    for (int j = 0; j < HC; ++j) x[j] = xrow[j];
    const float* Qc = qk + c * HC;
    #pragma unroll
    for (int n = 0; n < NSIG; ++n) {
      const float* Qn = Qc + (size_t)n * HID;   // uniform address -> s_load
      float s = 0.f;
      #pragma unroll
      for (int j = 0; j < HC; ++j) s = fmaf(x[j], Qn[j], s);
      acc[n] += s;
    }
  }

  // ---- Block-local softmax partials: m_p, l_p, pa_p per signal
  const int wv = t >> 6;
  float mloc[NSIG];
  #pragma unroll
  for (int n = 0; n < NSIG; ++n) {
    float v = acc[n];
    #pragma unroll
    for (int o = 32; o > 0; o >>= 1) v = fmaxf(v, __shfl_xor(v, o, 64));
    mloc[n] = v;
  }
  __syncthreads();                       // done reading smem as X staging
  float* wS   = smem;                    // [15][256] unnormalized e^(a-m_p)
  float* redM = smem + NSIG * SC;        // [15][4]
  float* redL = redM + NSIG * 4;
  float* redP = redL + NSIG * 4;
  if ((t & 63) == 0) {
    #pragma unroll
    for (int n = 0; n < NSIG; ++n) redM[n * 4 + wv] = mloc[n];
  }
  __syncthreads();
  #pragma unroll
  for (int n = 0; n < NSIG; ++n) {
    float m = fmaxf(fmaxf(redM[n*4+0], redM[n*4+1]), fmaxf(redM[n*4+2], redM[n*4+3]));
    float e = expf(acc[n] - m);
    wS[n * SC + t] = e;
    float l = e, pa = e * acc[n];
    #pragma unroll
    for (int o = 32; o > 0; o >>= 1) { l += __shfl_xor(l, o, 64); pa += __shfl_xor(pa, o, 64); }
    if ((t & 63) == 0) { redL[n * 4 + wv] = l; redP[n * 4 + wv] = pa; }
  }
  __syncthreads();
  if (t < NSIG) {
    float m  = fmaxf(fmaxf(redM[t*4+0], redM[t*4+1]), fmaxf(redM[t*4+2], redM[t*4+3]));
    float l  = redL[t*4+0] + redL[t*4+1] + redL[t*4+2] + redL[t*4+3];
    float pa = redP[t*4+0] + redP[t*4+1] + redP[t*4+2] + redP[t*4+3];
    float* st = stats + ((size_t)((b * NCHUNK + chunk) * NSIG + t)) * 3;
    st[0] = m; st[1] = l; st[2] = pa;
  }

  // ---- Pass B: unnormalized ctx partials; thread owns h-cols {t, t+256, t+512}
  // X re-read from global (L3-warm: this block just streamed it)
  float accB[NSIG * 3];
  #pragma unroll
  for (int i = 0; i < NSIG * 3; ++i) accB[i] = 0.f;
  const float* Xc = Xb + t;
  for (int s = 0; s < SC; s += 4) {
    float x[12];
    #pragma unroll
    for (int j = 0; j < 4; ++j)
      #pragma unroll
      for (int k = 0; k < 3; ++k)
        x[j * 3 + k] = Xc[(size_t)(s + j) * HID + k * 256];   // coalesced b32
    #pragma unroll
    for (int n = 0; n < NSIG; ++n) {
      float4 w4 = *(const float4*)(wS + n * SC + s);           // broadcast b128
      float wa[4] = {w4.x, w4.y, w4.z, w4.w};
      #pragma unroll
      for (int j = 0; j < 4; ++j)
        #pragma unroll
        for (int k = 0; k < 3; ++k)
          accB[n * 3 + k] = fmaf(wa[j], x[j * 3 + k], accB[n * 3 + k]);
    }
  }
  float* dst = ctxp + ((size_t)((b * NCHUNK + chunk) * NSIG)) * HID + t;
  #pragma unroll
  for (int n = 0; n < NSIG; ++n)
    #pragma unroll
    for (int k = 0; k < 3; ++k)
      dst[(size_t)n * HID + k * 256] = accB[n * 3 + k];        // coalesced
}

// ---------------- Final: combine partials, entropy/strength, ctx·Wv, gelu MLP
__global__ __launch_bounds__(256) void k_final(const float* __restrict__ stats,
                                               const float* __restrict__ ctxp,
                                               const float* __restrict__ Wv,
                                               const float* __restrict__ bv,
                                               const float* __restrict__ nullemb,
                                               const float* __restrict__ W1,
                                               const float* __restrict__ b1,
                                               const float* __restrict__ W2,
                                               const float* __restrict__ b2,
                                               float* __restrict__ out) {
  const int blk = blockIdx.x;                  // 0..479
  const int b = blk / NSIG, n = blk - b * NSIG;
  const int t = threadIdx.x;
  __shared__ float alpha[NCHUNK];
  __shared__ float ctx[HID];
  __shared__ float se[DIMD];

  if (t == 0) {
    float mc[NCHUNK], lc[NCHUNK], pc[NCHUNK];
    float m = -1e30f;
    #pragma unroll
    for (int c = 0; c < NCHUNK; ++c) {
      const float* st = stats + ((size_t)((b * NCHUNK + c) * NSIG + n)) * 3;
      mc[c] = st[0]; lc[c] = st[1]; pc[c] = st[2];
      m = fmaxf(m, mc[c]);
    }
    float L = 0.f, PA = 0.f;
    #pragma unroll
    for (int c = 0; c < NCHUNK; ++c) {
      float scl = expf(mc[c] - m);
      L = fmaf(scl, lc[c], L); PA = fmaf(scl, pc[c], PA);
    }
    #pragma unroll
    for (int c = 0; c < NCHUNK; ++c) alpha[c] = expf(mc[c] - m) / L;
    float entropy = m + logf(L) - PA / L;
    out[b * (2 * NSIG) + NSIG + n] = 1.f - entropy / LOG_S;
  }
  __syncthreads();

  #pragma unroll
  for (int k = 0; k < 3; ++k) {
    int h = t + k * 256;
    float s = 0.f;
    #pragma unroll
    for (int c = 0; c < NCHUNK; ++c)
      s = fmaf(alpha[c], ctxp[((size_t)((b * NCHUNK + c) * NSIG + n)) * HID + h], s);
    ctx[h] = s;
  }
  __syncthreads();

  if (t < DIMD) {
    float s = bv[t];
    #pragma unroll 4
    for (int h = 0; h < HID; ++h)
      s = fmaf(ctx[h], Wv[(size_t)h * DIMD + t], s);
    se[t] = s;
  }
  __syncthreads();

  if (t < 64) {
    float s = b1[t];
    const float* nrow = nullemb + (size_t)n * HID;
    #pragma unroll 4
    for (int i = 0; i < DIMD; ++i) s = fmaf(se[i],   W1[(size_t)i * 64 + t], s);
    #pragma unroll 4
    for (int i = 0; i < DIMD; ++i) s = fmaf(nrow[i], W1[(size_t)(DIMD + i) * 64 + t], s);
    float g = 0.5f * s * (1.f + erff(s * 0.70710678118654752f));  // exact gelu
    float val = g * W2[t];
    #pragma unroll
    for (int o = 32; o > 0; o >>= 1) val += __shfl_down(val, o, 64);
    if (t == 0) out[b * (2 * NSIG) + n] = val + b2[0];
  }
}

extern "C" void kernel_launch(void* const* d_in, const int* in_sizes, int n_in,
                              void* d_out, int out_size, void* d_ws, size_t ws_size,
                              hipStream_t stream) {
  const float* X   = (const float*)d_in[0];
  const float* Wk  = (const float*)d_in[1];
  const float* bk  = (const float*)d_in[2];
  const float* Wv  = (const float*)d_in[3];
  const float* bv  = (const float*)d_in[4];
  const float* q   = (const float*)d_in[5];
  const float* nul = (const float*)d_in[6];
  const float* W1  = (const float*)d_in[7];
  const float* b1  = (const float*)d_in[8];
  const float* W2  = (const float*)d_in[9];
  const float* b2  = (const float*)d_in[10];
  float* out = (float*)d_out;
  float* ws  = (float*)d_ws;    // ~24 MB used

  hipLaunchKernelGGL(k_qk, dim3(45), dim3(256), 0, stream, q, Wk, bk, ws);
  hipLaunchKernelGGL(k_fused, dim3(NCHUNK, BB), dim3(256), 0, stream,
                     X, ws + WS_QK, ws + WS_QB, ws + WS_ST, ws + WS_CTXP);
  hipLaunchKernelGGL(k_final, dim3(BB * NSIG), dim3(256), 0, stream,
                     ws + WS_ST, ws + WS_CTXP, Wv, bv, nul, W1, b1, W2, b2, out);
}

// Round 3
// 819.400 us; speedup vs baseline: 1.0905x; 1.0905x over previous
//
#include <hip/hip_runtime.h>
#include <math.h>

// Problem constants
#define HID   768
#define DIMD  192
#define NSIG  15
#define BB    32
#define SS    4096
#define SC    128                 // tokens per fused block
#define NCHUNK (SS / SC)          // 32
#define HC    32                  // h-cols staged per iteration (per half)
#define NHC   (384 / HC)          // 12 chunk iterations
#define INV_SCALE 0.07216878364870322f   // 1/sqrt(192)
#define LOG_S     8.31776616671934f      // ln(4096)

// Workspace layout (floats)
#define WS_QK   ((size_t)0)                      // [15][768] scaled Q
#define WS_QB   (WS_QK + NSIG * HID)             // [15] scaled bias dot
#define WS_ST   (WS_QB + 16)                     // [B][32][15][3] m,l,pa partials
#define WS_CTXP (WS_ST + (size_t)BB * NCHUNK * NSIG * 3)  // [B][32][15][768]

// ---------------- Kernel A: Qk[n][h] = (q[n,:]·Wk[h,:])/sqrt(d), qb[n] = (q[n]·bk)/sqrt(d)
__global__ __launch_bounds__(256) void k_qk(const float* __restrict__ q,
                                            const float* __restrict__ Wk,
                                            const float* __restrict__ bk,
                                            float* __restrict__ ws) {
  int idx = blockIdx.x * 256 + threadIdx.x;
  if (idx < NSIG * HID) {
    int n = idx / HID, h = idx - n * HID;
    const float* qr = q + n * DIMD;
    const float* wr = Wk + h * DIMD;
    float s = 0.f;
    #pragma unroll 4
    for (int d = 0; d < DIMD; ++d) s = fmaf(qr[d], wr[d], s);
    ws[WS_QK + (size_t)n * HID + h] = s * INV_SCALE;
  }
  if (idx < NSIG) {
    const float* qr = q + idx * DIMD;
    float s = 0.f;
    for (int d = 0; d < DIMD; ++d) s = fmaf(qr[d], bk[d], s);
    ws[WS_QB + idx] = s * INV_SCALE;
  }
}

// ---------------- Fused: logits -> local softmax partials -> ctx partials
// Block = (128-token chunk, b): 1024 blocks -> 4 blocks/CU, 16 waves/CU.
// Threads: tk = t&127 (token), hf = t>>7 (h-half, wave-uniform). Register
// double-buffered LDS staging; Q via wave-uniform scalar loads.
__global__ __launch_bounds__(256, 4) void k_fused(const float* __restrict__ X,
                                                  const float* __restrict__ qk,
                                                  const float* __restrict__ qb,
                                                  float* __restrict__ stats,
                                                  float* __restrict__ ctxp) {
  __shared__ float smem[2 * SC * 33];     // 33792 B; reused post-passA
  const int t = threadIdx.x;
  const int chunk = blockIdx.x, b = blockIdx.y;
  const int tk = t & (SC - 1);
  const int hf = __builtin_amdgcn_readfirstlane(t >> 7);   // wave-uniform half
  const float* Xb = X + ((size_t)(b * SS + chunk * SC)) * HID;

  // Thread's 8 staging float4s: j = t + k*256 -> (half, row, col4)
  float4 r[8];
  #pragma unroll
  for (int k = 0; k < 8; ++k) {
    int j = t + k * 256;
    int c4 = j & 7, row = (j >> 3) & (SC - 1), half = j >> 10;
    r[k] = *(const float4*)(Xb + (size_t)row * HID + half * 384 + c4 * 4);
  }

  float acc[NSIG];
  #pragma unroll
  for (int n = 0; n < NSIG; ++n) acc[n] = (hf == 0) ? qb[n] : 0.f;

  for (int c = 0; c < NHC; ++c) {         // 12 h-chunks per half
    __syncthreads();                      // readers of tile c-1 done
    #pragma unroll
    for (int k = 0; k < 8; ++k) {         // store regs -> LDS (b32, stride-33)
      int j = t + k * 256;
      int c4 = j & 7, row = (j >> 3) & (SC - 1), half = j >> 10;
      float* dst = smem + (half * SC + row) * 33 + c4 * 4;
      dst[0] = r[k].x; dst[1] = r[k].y; dst[2] = r[k].z; dst[3] = r[k].w;
    }
    __syncthreads();                      // tile c ready
    if (c + 1 < NHC) {                    // prefetch tile c+1 into regs
      #pragma unroll
      for (int k = 0; k < 8; ++k) {
        int j = t + k * 256;
        int c4 = j & 7, row = (j >> 3) & (SC - 1), half = j >> 10;
        r[k] = *(const float4*)(Xb + (size_t)row * HID + half * 384 + (c + 1) * HC + c4 * 4);
      }
    }
    const float* xrow = smem + (hf * SC + tk) * 33;   // conflict-free b32 reads
    float x[HC];
    #pragma unroll
    for (int j = 0; j < HC; ++j) x[j] = xrow[j];
    const float* Qc = qk + hf * 384 + c * HC;         // wave-uniform -> s_load
    #pragma unroll
    for (int n = 0; n < NSIG; ++n) {
      const float* Qn = Qc + (size_t)n * HID;
      float s = 0.f;
      #pragma unroll
      for (int j = 0; j < HC; ++j) s = fmaf(x[j], Qn[j], s);
      acc[n] += s;
    }
  }

  // ---- combine h-halves + block-local softmax partials (LDS region reuse)
  __syncthreads();                        // pass-A LDS reads done
  float* comb = smem;                     // [15][128]
  float* wS   = smem + NSIG * SC;         // [15][128] e^(a - m_chunk)
  float* redM = smem + 2 * NSIG * SC;     // [15][2]
  float* redL = redM + NSIG * 2;
  float* redP = redL + NSIG * 2;
  const int wv = __builtin_amdgcn_readfirstlane(t >> 6);

  if (hf == 1) {
    #pragma unroll
    for (int n = 0; n < NSIG; ++n) comb[n * SC + tk] = acc[n];
  }
  __syncthreads();
  if (hf == 0) {
    #pragma unroll
    for (int n = 0; n < NSIG; ++n) {
      acc[n] += comb[n * SC + tk];
      float v = acc[n];
      #pragma unroll
      for (int o = 32; o > 0; o >>= 1) v = fmaxf(v, __shfl_xor(v, o, 64));
      if ((t & 63) == 0) redM[n * 2 + wv] = v;
    }
  }
  __syncthreads();
  if (hf == 0) {
    #pragma unroll
    for (int n = 0; n < NSIG; ++n) {
      float m = fmaxf(redM[n * 2], redM[n * 2 + 1]);
      float e = expf(acc[n] - m);
      wS[n * SC + tk] = e;
      float l = e, pa = e * acc[n];
      #pragma unroll
      for (int o = 32; o > 0; o >>= 1) { l += __shfl_xor(l, o, 64); pa += __shfl_xor(pa, o, 64); }
      if ((t & 63) == 0) { redL[n * 2 + wv] = l; redP[n * 2 + wv] = pa; }
    }
  }
  __syncthreads();
  if (t < NSIG) {
    float m  = fmaxf(redM[t * 2], redM[t * 2 + 1]);
    float l  = redL[t * 2] + redL[t * 2 + 1];
    float pa = redP[t * 2] + redP[t * 2 + 1];
    float* st = stats + ((size_t)((b * NCHUNK + chunk) * NSIG + t)) * 3;
    st[0] = m; st[1] = l; st[2] = pa;
  }

  // ---- Pass B: unnormalized ctx partials; thread owns h-cols {t, t+256, t+512}
  float accB[NSIG * 3];
  #pragma unroll
  for (int i = 0; i < NSIG * 3; ++i) accB[i] = 0.f;
  const float* Xc = Xb + t;
  for (int s = 0; s < SC; s += 4) {
    float x[12];
    #pragma unroll
    for (int j = 0; j < 4; ++j)
      #pragma unroll
      for (int k = 0; k < 3; ++k)
        x[j * 3 + k] = Xc[(size_t)(s + j) * HID + k * 256];   // coalesced, L2/L3-warm
    #pragma unroll
    for (int n = 0; n < NSIG; ++n) {
      float4 w4 = *(const float4*)(wS + n * SC + s);           // broadcast b128
      float wa[4] = {w4.x, w4.y, w4.z, w4.w};
      #pragma unroll
      for (int j = 0; j < 4; ++j)
        #pragma unroll
        for (int k = 0; k < 3; ++k)
          accB[n * 3 + k] = fmaf(wa[j], x[j * 3 + k], accB[n * 3 + k]);
    }
  }
  float* dst = ctxp + ((size_t)((b * NCHUNK + chunk) * NSIG)) * HID + t;
  #pragma unroll
  for (int n = 0; n < NSIG; ++n)
    #pragma unroll
    for (int k = 0; k < 3; ++k)
      dst[(size_t)n * HID + k * 256] = accB[n * 3 + k];        // coalesced
}

// ---------------- Final: combine partials, entropy/strength, ctx·Wv, gelu MLP
__global__ __launch_bounds__(256) void k_final(const float* __restrict__ stats,
                                               const float* __restrict__ ctxp,
                                               const float* __restrict__ Wv,
                                               const float* __restrict__ bv,
                                               const float* __restrict__ nullemb,
                                               const float* __restrict__ W1,
                                               const float* __restrict__ b1,
                                               const float* __restrict__ W2,
                                               const float* __restrict__ b2,
                                               float* __restrict__ out) {
  const int blk = blockIdx.x;                  // 0..479
  const int b = blk / NSIG, n = blk - b * NSIG;
  const int t = threadIdx.x;
  __shared__ float alpha[NCHUNK];
  __shared__ float ctx[HID];
  __shared__ float se[DIMD];

  if (t == 0) {
    float mc[NCHUNK], lc[NCHUNK], pc[NCHUNK];
    float m = -1e30f;
    #pragma unroll
    for (int c = 0; c < NCHUNK; ++c) {
      const float* st = stats + ((size_t)((b * NCHUNK + c) * NSIG + n)) * 3;
      mc[c] = st[0]; lc[c] = st[1]; pc[c] = st[2];
      m = fmaxf(m, mc[c]);
    }
    float L = 0.f, PA = 0.f;
    #pragma unroll
    for (int c = 0; c < NCHUNK; ++c) {
      float scl = expf(mc[c] - m);
      L = fmaf(scl, lc[c], L); PA = fmaf(scl, pc[c], PA);
    }
    #pragma unroll
    for (int c = 0; c < NCHUNK; ++c) alpha[c] = expf(mc[c] - m) / L;
    float entropy = m + logf(L) - PA / L;
    out[b * (2 * NSIG) + NSIG + n] = 1.f - entropy / LOG_S;
  }
  __syncthreads();

  #pragma unroll
  for (int k = 0; k < 3; ++k) {
    int h = t + k * 256;
    float s = 0.f;
    #pragma unroll 8
    for (int c = 0; c < NCHUNK; ++c)
      s = fmaf(alpha[c], ctxp[((size_t)((b * NCHUNK + c) * NSIG + n)) * HID + h], s);
    ctx[h] = s;
  }
  __syncthreads();

  if (t < DIMD) {
    float s = bv[t];
    #pragma unroll 4
    for (int h = 0; h < HID; ++h)
      s = fmaf(ctx[h], Wv[(size_t)h * DIMD + t], s);
    se[t] = s;
  }
  __syncthreads();

  if (t < 64) {
    float s = b1[t];
    const float* nrow = nullemb + (size_t)n * HID;
    #pragma unroll 4
    for (int i = 0; i < DIMD; ++i) s = fmaf(se[i],   W1[(size_t)i * 64 + t], s);
    #pragma unroll 4
    for (int i = 0; i < DIMD; ++i) s = fmaf(nrow[i], W1[(size_t)(DIMD + i) * 64 + t], s);
    float g = 0.5f * s * (1.f + erff(s * 0.70710678118654752f));  // exact gelu
    float val = g * W2[t];
    #pragma unroll
    for (int o = 32; o > 0; o >>= 1) val += __shfl_down(val, o, 64);
    if (t == 0) out[b * (2 * NSIG) + n] = val + b2[0];
  }
}

extern "C" void kernel_launch(void* const* d_in, const int* in_sizes, int n_in,
                              void* d_out, int out_size, void* d_ws, size_t ws_size,
                              hipStream_t stream) {
  const float* X   = (const float*)d_in[0];
  const float* Wk  = (const float*)d_in[1];
  const float* bk  = (const float*)d_in[2];
  const float* Wv  = (const float*)d_in[3];
  const float* bv  = (const float*)d_in[4];
  const float* q   = (const float*)d_in[5];
  const float* nul = (const float*)d_in[6];
  const float* W1  = (const float*)d_in[7];
  const float* b1  = (const float*)d_in[8];
  const float* W2  = (const float*)d_in[9];
  const float* b2  = (const float*)d_in[10];
  float* out = (float*)d_out;
  float* ws  = (float*)d_ws;    // ~48 MB used

  hipLaunchKernelGGL(k_qk, dim3(45), dim3(256), 0, stream, q, Wk, bk, ws);
  hipLaunchKernelGGL(k_fused, dim3(NCHUNK, BB), dim3(256), 0, stream,
                     X, ws + WS_QK, ws + WS_QB, ws + WS_ST, ws + WS_CTXP);
  hipLaunchKernelGGL(k_final, dim3(BB * NSIG), dim3(256), 0, stream,
                     ws + WS_ST, ws + WS_CTXP, Wv, bv, nul, W1, b1, W2, b2, out);
}